// Round 2
// baseline (765.847 us; speedup 1.0000x reference)
//
#include <hip/hip_runtime.h>
#include <hip/hip_bf16.h>

#define HEADS 8
#define DIM 128

// ---------------------------------------------------------------------------
// edge_index dtype normalization: reference declares int64; harness may pass
// int32. Detect on-device (int64 => high words ~all zero), convert to int32.
// ---------------------------------------------------------------------------
__global__ void detect_width_k(const unsigned int* __restrict__ w, int* __restrict__ flag) {
    __shared__ int cnt;
    if (threadIdx.x == 0) cnt = 0;
    __syncthreads();
    // examine odd 32-bit words among the first 512 words
    if (w[2 * threadIdx.x + 1] == 0u) atomicAdd(&cnt, 1);
    __syncthreads();
    if (threadIdx.x == 0) flag[0] = (cnt > 192) ? 1 : 0;
}

__global__ void cvt_edges_k(const void* __restrict__ ei, const int* __restrict__ flag,
                            int n2, int* __restrict__ out) {
    int i = blockIdx.x * 256 + threadIdx.x;
    if (i < n2) {
        if (flag[0])
            out[i] = (int)((const long long*)ei)[i];
        else
            out[i] = ((const int*)ei)[i];
    }
}

// ---------------------------------------------------------------------------
// CSR build kernels
// ---------------------------------------------------------------------------
__global__ void count_deg_k(const int* __restrict__ rows, int E, int* __restrict__ deg) {
    int e = blockIdx.x * 256 + threadIdx.x;
    if (e < E) atomicAdd(&deg[rows[e]], 1);
}

__global__ void scan1_k(const int* __restrict__ deg, int n,
                        int* __restrict__ incl, int* __restrict__ blkSums) {
    __shared__ int s[256];
    int i = blockIdx.x * 256 + threadIdx.x;
    int v = (i < n) ? deg[i] : 0;
    s[threadIdx.x] = v;
    __syncthreads();
    for (int off = 1; off < 256; off <<= 1) {
        int t = (threadIdx.x >= off) ? s[threadIdx.x - off] : 0;
        __syncthreads();
        s[threadIdx.x] += t;
        __syncthreads();
    }
    if (i < n) incl[i] = s[threadIdx.x];
    if (threadIdx.x == 255) blkSums[blockIdx.x] = s[255];
}

// single block, nb <= 256: make blkSums exclusive-scanned in place
__global__ void scan2_k(int* __restrict__ blkSums, int nb) {
    __shared__ int s[256];
    int v = (threadIdx.x < nb) ? blkSums[threadIdx.x] : 0;
    s[threadIdx.x] = v;
    __syncthreads();
    for (int off = 1; off < 256; off <<= 1) {
        int t = (threadIdx.x >= off) ? s[threadIdx.x - off] : 0;
        __syncthreads();
        s[threadIdx.x] += t;
        __syncthreads();
    }
    if (threadIdx.x < nb) blkSums[threadIdx.x] = s[threadIdx.x] - v;  // exclusive
}

__global__ void scan3_k(const int* __restrict__ incl, const int* __restrict__ deg,
                        const int* __restrict__ blkOff, int n,
                        int* __restrict__ rowPtr, int* __restrict__ cursor) {
    int i = blockIdx.x * 256 + threadIdx.x;
    if (i < n) {
        int inc = incl[i] + blkOff[blockIdx.x];
        rowPtr[i + 1] = inc;
        cursor[i] = inc - deg[i];
    }
    if (i == 0) rowPtr[0] = 0;
}

__global__ void scatter_k(const int* __restrict__ rows, const int* __restrict__ cols, int E,
                          int* __restrict__ cursor, int* __restrict__ colIdx) {
    int e = blockIdx.x * 256 + threadIdx.x;
    if (e < E) {
        int pos = atomicAdd(&cursor[rows[e]], 1);
        colIdx[pos] = cols[e];
    }
}

// ---------------------------------------------------------------------------
// Tiled GEMM, all f32: Out[M,NOUT] = A[M,K] @ W[K,NOUT] (+ b0 + b1)
// Block: 256 threads, tile 32 rows x NOUT cols, f32 accumulate.
// ---------------------------------------------------------------------------
template <int K, int NOUT, bool HAS_BIAS>
__global__ __launch_bounds__(256) void gemm_k(
    const float* __restrict__ A, const float* __restrict__ W,
    const float* __restrict__ b0, const float* __restrict__ b1,
    float* __restrict__ Out, int M)
{
    constexpr int BM = 32;
    constexpr int KB = 8;
    constexpr int NC = NOUT / 128;  // float4 chunks per thread (1 or 2)
    __shared__ float As[BM][KB];
    __shared__ float Ws[KB][NOUT];

    const int tid = threadIdx.x;
    const int tx = tid & 31;   // col group: cols [tx*4, tx*4+4) (+ c*128)
    const int ty = tid >> 5;   // row group: rows [ty*4, ty*4+4)
    const int row0 = blockIdx.x * BM;

    float4 acc[4][NC];
#pragma unroll
    for (int j = 0; j < 4; j++)
#pragma unroll
        for (int c = 0; c < NC; c++) acc[j][c] = make_float4(0.f, 0.f, 0.f, 0.f);

    for (int k0 = 0; k0 < K; k0 += KB) {
        // stage A: 32x8 = 256 elements, one per thread
        {
            int r = tid >> 3, kk = tid & 7;
            int gr = row0 + r;
            As[r][kk] = (gr < M) ? A[(size_t)gr * K + k0 + kk] : 0.f;
        }
        // stage W: KB x NOUT floats via float4
        {
            const float4* W4 = (const float4*)(W + (size_t)k0 * NOUT);
            float4* Ws4 = (float4*)&Ws[0][0];
            constexpr int N4 = KB * NOUT / 4;  // 256 or 512
#pragma unroll
            for (int j = 0; j < N4 / 256; j++)
                Ws4[tid + j * 256] = W4[tid + j * 256];
        }
        __syncthreads();
#pragma unroll
        for (int kk = 0; kk < KB; kk++) {
            float a0 = As[ty * 4 + 0][kk];
            float a1 = As[ty * 4 + 1][kk];
            float a2 = As[ty * 4 + 2][kk];
            float a3 = As[ty * 4 + 3][kk];
#pragma unroll
            for (int c = 0; c < NC; c++) {
                float4 w = *(const float4*)&Ws[kk][c * 128 + tx * 4];
                acc[0][c].x += a0 * w.x; acc[0][c].y += a0 * w.y; acc[0][c].z += a0 * w.z; acc[0][c].w += a0 * w.w;
                acc[1][c].x += a1 * w.x; acc[1][c].y += a1 * w.y; acc[1][c].z += a1 * w.z; acc[1][c].w += a1 * w.w;
                acc[2][c].x += a2 * w.x; acc[2][c].y += a2 * w.y; acc[2][c].z += a2 * w.z; acc[2][c].w += a2 * w.w;
                acc[3][c].x += a3 * w.x; acc[3][c].y += a3 * w.y; acc[3][c].z += a3 * w.z; acc[3][c].w += a3 * w.w;
            }
        }
        __syncthreads();
    }

    // epilogue
#pragma unroll
    for (int j = 0; j < 4; j++) {
        int gr = row0 + ty * 4 + j;
        if (gr >= M) continue;
#pragma unroll
        for (int c = 0; c < NC; c++) {
            int col = c * 128 + tx * 4;
            float4 v = acc[j][c];
            if (HAS_BIAS) {
                if (b0) {
                    v.x += b0[col + 0]; v.y += b0[col + 1];
                    v.z += b0[col + 2]; v.w += b0[col + 3];
                }
                if (b1) {
                    v.x += b1[col + 0]; v.y += b1[col + 1];
                    v.z += b1[col + 2]; v.w += b1[col + 3];
                }
            }
            *reinterpret_cast<float4*>(&Out[(size_t)gr * NOUT + col]) = v;
        }
    }
}

// ---------------------------------------------------------------------------
// Fused per-node attention + residual + LayerNorm.
// One block (128 threads) per node. tid = feature dim; head = tid>>4.
// ---------------------------------------------------------------------------
__global__ __launch_bounds__(128) void agg_k(
    const float* __restrict__ Q, const float* __restrict__ Kt, const float* __restrict__ Vt,
    const int* __restrict__ rowPtr, const int* __restrict__ colIdx,
    const float* __restrict__ ln_s, const float* __restrict__ ln_b,
    float* __restrict__ embeds, int n)
{
    int i = blockIdx.x;
    if (i >= n) return;
    int tid = threadIdx.x;

    float q = Q[(size_t)i * DIM + tid];
    float resid = embeds[(size_t)i * DIM + tid];
    int e0 = rowPtr[i], e1 = rowPtr[i + 1];

    float acc = 0.f, denom = 0.f;
    for (int e = e0; e < e1; e++) {
        int c = colIdx[e];
        float kv = Kt[(size_t)c * DIM + tid];
        float p = q * kv;
        // reduce over the 16 lanes of this head
        p += __shfl_xor(p, 1);
        p += __shfl_xor(p, 2);
        p += __shfl_xor(p, 4);
        p += __shfl_xor(p, 8);
        float att = fminf(fmaxf(p, -10.f), 10.f);
        float w = expf(att);
        denom += w;
        acc += w * Vt[(size_t)c * DIM + tid];
    }
    float out = acc / (denom + 1e-8f) + resid;

    // LayerNorm over 128 dims (2 waves)
    float s = out, s2 = out * out;
#pragma unroll
    for (int m = 1; m < 64; m <<= 1) {
        s  += __shfl_xor(s, m);
        s2 += __shfl_xor(s2, m);
    }
    __shared__ float wsum[2][2];
    int wid = tid >> 6;
    if ((tid & 63) == 0) { wsum[0][wid] = s; wsum[1][wid] = s2; }
    __syncthreads();
    s  = wsum[0][0] + wsum[0][1];
    s2 = wsum[1][0] + wsum[1][1];
    float mu = s * (1.f / 128.f);
    float var = s2 * (1.f / 128.f) - mu * mu;
    float r = rsqrtf(var + 1e-6f);
    float y = (out - mu) * r * ln_s[tid] + ln_b[tid];
    embeds[(size_t)i * DIM + tid] = y;
}

// ---------------------------------------------------------------------------
// Launch
// ---------------------------------------------------------------------------
extern "C" void kernel_launch(void* const* d_in, const int* in_sizes, int n_in,
                              void* d_out, int out_size, void* d_ws, size_t ws_size,
                              hipStream_t stream)
{
    const float* x    = (const float*)d_in[0];
    const void*  ei   = d_in[1];
    const float* Wp   = (const float*)d_in[2];
    const float* Wpb  = (const float*)d_in[3];
    const float* Wpos = (const float*)d_in[4];
    const float* q1   = (const float*)d_in[5];
    const float* k1   = (const float*)d_in[6];
    const float* v1   = (const float*)d_in[7];
    const float* l1s  = (const float*)d_in[8];
    const float* l1b  = (const float*)d_in[9];
    const float* q2   = (const float*)d_in[10];
    const float* k2   = (const float*)d_in[11];
    const float* v2   = (const float*)d_in[12];
    const float* l2s  = (const float*)d_in[13];
    const float* l2b  = (const float*)d_in[14];
    const float* invw = (const float*)d_in[15];
    const float* invb = (const float*)d_in[16];

    const int N = in_sizes[0] / 256;   // 50000
    const int E = in_sizes[1] / 2;     // 800000

    // carve workspace
    char* p = (char*)d_ws;
    auto carve = [&](size_t bytes) -> void* {
        void* r = (void*)p;
        p += (bytes + 255) & ~(size_t)255;
        return r;
    };
    float* embeds = (float*)carve((size_t)N * DIM * 4);
    float* Qb     = (float*)carve((size_t)N * DIM * 4);
    float* Kb     = (float*)carve((size_t)N * DIM * 4);
    float* Vb     = (float*)carve((size_t)N * DIM * 4);
    int*   deg    = (int*)carve((size_t)N * 4);
    int*   incl   = (int*)carve((size_t)N * 4);
    int*   blkS   = (int*)carve(1024);
    int*   rowPtr = (int*)carve((size_t)(N + 1) * 4);
    int*   cursor = (int*)carve((size_t)N * 4);
    int*   colIdx = (int*)carve((size_t)E * 4);
    int*   rc     = (int*)carve((size_t)2 * E * 4);  // normalized int32 rows|cols
    int*   wflag  = (int*)carve(256);

    int* rows = rc;
    int* cols = rc + E;

    const int nb  = (N + 255) / 256;
    const int ebl = (E + 255) / 256;
    const int gbl = (N + 31) / 32;

    // normalize edge_index to int32
    detect_width_k<<<1, 256, 0, stream>>>((const unsigned int*)ei, wflag);
    cvt_edges_k<<<(2 * E + 255) / 256, 256, 0, stream>>>(ei, wflag, 2 * E, rc);

    // CSR build (edge_index is identical for both layers)
    hipMemsetAsync(deg, 0, (size_t)N * 4, stream);
    count_deg_k<<<ebl, 256, 0, stream>>>(rows, E, deg);
    scan1_k<<<nb, 256, 0, stream>>>(deg, N, incl, blkS);
    scan2_k<<<1, 256, 0, stream>>>(blkS, nb);
    scan3_k<<<nb, 256, 0, stream>>>(incl, deg, blkS, N, rowPtr, cursor);
    scatter_k<<<ebl, 256, 0, stream>>>(rows, cols, E, cursor, colIdx);

    // input projection: embeds = x @ W_P + b + pos
    gemm_k<256, 128, true><<<gbl, 256, 0, stream>>>(x, Wp, Wpb, Wpos, embeds, N);

    // layer 1
    gemm_k<128, 128, false><<<gbl, 256, 0, stream>>>(embeds, q1, nullptr, nullptr, Qb, N);
    gemm_k<128, 128, false><<<gbl, 256, 0, stream>>>(embeds, k1, nullptr, nullptr, Kb, N);
    gemm_k<128, 128, false><<<gbl, 256, 0, stream>>>(embeds, v1, nullptr, nullptr, Vb, N);
    agg_k<<<N, 128, 0, stream>>>(Qb, Kb, Vb, rowPtr, colIdx, l1s, l1b, embeds, N);

    // layer 2
    gemm_k<128, 128, false><<<gbl, 256, 0, stream>>>(embeds, q2, nullptr, nullptr, Qb, N);
    gemm_k<128, 128, false><<<gbl, 256, 0, stream>>>(embeds, k2, nullptr, nullptr, Kb, N);
    gemm_k<128, 128, false><<<gbl, 256, 0, stream>>>(embeds, v2, nullptr, nullptr, Vb, N);
    agg_k<<<N, 128, 0, stream>>>(Qb, Kb, Vb, rowPtr, colIdx, l2s, l2b, embeds, N);

    // output projection: out = embeds @ inv_w + inv_b  (f32)
    gemm_k<128, 256, true><<<gbl, 256, 0, stream>>>(embeds, invw, invb, nullptr, (float*)d_out, N);
}

// Round 4
// 671.675 us; speedup vs baseline: 1.1402x; 1.1402x over previous
//
#include <hip/hip_runtime.h>
#include <hip/hip_bf16.h>

#define HEADS 8
#define DIM 128

typedef short s8v __attribute__((ext_vector_type(8)));
typedef float f4v __attribute__((ext_vector_type(4)));

__device__ __forceinline__ float bf2f(unsigned int lo16) {
    union { unsigned int i; float f; } v; v.i = lo16 << 16; return v.f;
}
__device__ __forceinline__ unsigned short f2bf(float f) {
    __hip_bfloat16 h = __float2bfloat16(f);
    return *reinterpret_cast<unsigned short*>(&h);
}
__device__ __forceinline__ int imin(int a, int b) { return a < b ? a : b; }

// ---------------------------------------------------------------------------
// edge_index dtype normalization (int64 vs int32), validated in R2.
// ---------------------------------------------------------------------------
__global__ void detect_width_k(const unsigned int* __restrict__ w, int* __restrict__ flag) {
    __shared__ int cnt;
    if (threadIdx.x == 0) cnt = 0;
    __syncthreads();
    if (w[2 * threadIdx.x + 1] == 0u) atomicAdd(&cnt, 1);
    __syncthreads();
    if (threadIdx.x == 0) flag[0] = (cnt > 192) ? 1 : 0;
}

__global__ void cvt_edges_k(const void* __restrict__ ei, const int* __restrict__ flag,
                            int n2, int* __restrict__ out) {
    int i = blockIdx.x * 256 + threadIdx.x;
    if (i < n2) {
        if (flag[0])
            out[i] = (int)((const long long*)ei)[i];
        else
            out[i] = ((const int*)ei)[i];
    }
}

// ---------------------------------------------------------------------------
// CSR build kernels (unchanged, validated in R2)
// ---------------------------------------------------------------------------
__global__ void count_deg_k(const int* __restrict__ rows, int E, int* __restrict__ deg) {
    int e = blockIdx.x * 256 + threadIdx.x;
    if (e < E) atomicAdd(&deg[rows[e]], 1);
}

__global__ void scan1_k(const int* __restrict__ deg, int n,
                        int* __restrict__ incl, int* __restrict__ blkSums) {
    __shared__ int s[256];
    int i = blockIdx.x * 256 + threadIdx.x;
    int v = (i < n) ? deg[i] : 0;
    s[threadIdx.x] = v;
    __syncthreads();
    for (int off = 1; off < 256; off <<= 1) {
        int t = (threadIdx.x >= off) ? s[threadIdx.x - off] : 0;
        __syncthreads();
        s[threadIdx.x] += t;
        __syncthreads();
    }
    if (i < n) incl[i] = s[threadIdx.x];
    if (threadIdx.x == 255) blkSums[blockIdx.x] = s[255];
}

__global__ void scan2_k(int* __restrict__ blkSums, int nb) {
    __shared__ int s[256];
    int v = (threadIdx.x < nb) ? blkSums[threadIdx.x] : 0;
    s[threadIdx.x] = v;
    __syncthreads();
    for (int off = 1; off < 256; off <<= 1) {
        int t = (threadIdx.x >= off) ? s[threadIdx.x - off] : 0;
        __syncthreads();
        s[threadIdx.x] += t;
        __syncthreads();
    }
    if (threadIdx.x < nb) blkSums[threadIdx.x] = s[threadIdx.x] - v;
}

__global__ void scan3_k(const int* __restrict__ incl, const int* __restrict__ deg,
                        const int* __restrict__ blkOff, int n,
                        int* __restrict__ rowPtr, int* __restrict__ cursor) {
    int i = blockIdx.x * 256 + threadIdx.x;
    if (i < n) {
        int inc = incl[i] + blkOff[blockIdx.x];
        rowPtr[i + 1] = inc;
        cursor[i] = inc - deg[i];
    }
    if (i == 0) rowPtr[0] = 0;
}

__global__ void scatter_k(const int* __restrict__ rows, const int* __restrict__ cols, int E,
                          int* __restrict__ cursor, int* __restrict__ colIdx) {
    int e = blockIdx.x * 256 + threadIdx.x;
    if (e < E) {
        int pos = atomicAdd(&cursor[rows[e]], 1);
        colIdx[pos] = cols[e];
    }
}

// ---------------------------------------------------------------------------
// Build MFMA B-fragments from f32 W [Kd, Nd], `split` column phases and
// `ncomp` bf16 components (hi, lo = bf16(w - f32(hi))).
// dst frag index f = (comp*split + p)*perPhase + r, r = (nt*KS + ks)*64 + lane.
// Element j: W[ks*32 + (lane>>4)*8 + j][p*(Nd/split) + nt*16 + (lane&15)].
// ---------------------------------------------------------------------------
__global__ void build_wfrag_k(const float* __restrict__ W, unsigned short* __restrict__ dst,
                              int Kd, int Nd, int split, int ncomp) {
    int f = blockIdx.x * 256 + threadIdx.x;
    int KS = Kd >> 5;
    int perPhase = (Nd / 16 / split) * KS * 64;
    int total = ncomp * split * perPhase;
    if (f >= total) return;
    int comp = f / (split * perPhase);
    int r1 = f - comp * split * perPhase;
    int p = r1 / perPhase;
    int r = r1 - p * perPhase;
    int nt = r / (KS * 64);
    int r2 = r - nt * KS * 64;
    int ks = r2 >> 6, lane = r2 & 63;
    int n = p * (Nd / split) + nt * 16 + (lane & 15);
    int k0 = ks * 32 + (lane >> 4) * 8;
    unsigned short tmp[8];
#pragma unroll
    for (int j = 0; j < 8; j++) {
        float w = W[(size_t)(k0 + j) * Nd + n];
        unsigned short hi = f2bf(w);
        tmp[j] = (comp == 0) ? hi : f2bf(w - bf2f(hi));
    }
#pragma unroll
    for (int j = 0; j < 8; j++) dst[(size_t)f * 8 + j] = tmp[j];
}

// ---------------------------------------------------------------------------
// Split-bf16 MFMA GEMM: Out_m[M,NOUT] = A[M,K] @ W_m[K,NOUT] (+bias).
// A is f32; split at load into hi/lo bf16. NCOMP=2 computes
// Ah*Bh + Ah*Bl + Al*Bh (f32-quality); NCOMP=1 is plain bf16 MFMA.
// 512 threads = 8 waves; wave owns a pair of 16-row M-tiles.
// OUTBF_MASK bit m => mat m written bf16, else f32.
// ---------------------------------------------------------------------------
template<int K, int NOUT, int NMAT, int SPLIT, int NCOMP, int OUTBF_MASK, int NBIAS>
__global__ __launch_bounds__(512) void gemm_mfma_k(
    const float* __restrict__ A, const unsigned short* __restrict__ wfrag,
    const float* __restrict__ b0, const float* __restrict__ b1,
    void* __restrict__ o0p, void* __restrict__ o1p, void* __restrict__ o2p, int M)
{
    constexpr int KS = K / 32;
    constexpr int NTp = NOUT / 16 / SPLIT;
    constexpr int FRp = NTp * KS * 64;
    __shared__ s8v lds[NMAT * NCOMP * FRp];

    const int tid = threadIdx.x;
    const int lane = tid & 63;
    const int wid = tid >> 6;
    const int m16 = lane & 15, q4 = lane >> 4;
    const int wglob = blockIdx.x * 8 + wid;
    const int nw = gridDim.x * 8;
    const int nPairs = (M + 31) >> 5;
    void* outs[3] = { o0p, o1p, o2p };

    for (int p = 0; p < SPLIT; p++) {
        __syncthreads();
        for (int idx = tid; idx < NMAT * NCOMP * FRp; idx += 512) {
            int mat = idx / (NCOMP * FRp);
            int rem = idx - mat * NCOMP * FRp;
            int comp = rem / FRp;
            int r = rem - comp * FRp;
            lds[idx] = *(const s8v*)(wfrag + ((size_t)((mat * NCOMP + comp) * SPLIT + p) * FRp + r) * 8);
        }
        __syncthreads();

        for (int pr = wglob; pr < nPairs; pr += nw) {
            const int row0 = pr * 32;
            const int rA0 = imin(row0 + m16, M - 1);
            const int rA1 = imin(row0 + 16 + m16, M - 1);

            s8v a0h[KS], a1h[KS], a0l[KS], a1l[KS];
#pragma unroll
            for (int ks = 0; ks < KS; ks++) {
                const float* pa0 = A + (size_t)rA0 * K + ks * 32 + q4 * 8;
                const float* pa1 = A + (size_t)rA1 * K + ks * 32 + q4 * 8;
                s8v h0, h1, l0, l1;
#pragma unroll
                for (int j = 0; j < 8; j++) {
                    float x0 = pa0[j], x1 = pa1[j];
                    unsigned short hh0 = f2bf(x0), hh1 = f2bf(x1);
                    h0[j] = (short)hh0; h1[j] = (short)hh1;
                    if (NCOMP == 2) {
                        l0[j] = (short)f2bf(x0 - bf2f(hh0));
                        l1[j] = (short)f2bf(x1 - bf2f(hh1));
                    }
                }
                a0h[ks] = h0; a1h[ks] = h1;
                if (NCOMP == 2) { a0l[ks] = l0; a1l[ks] = l1; }
            }

            f4v acc0[NMAT][NTp], acc1[NMAT][NTp];
#pragma unroll
            for (int m = 0; m < NMAT; m++)
#pragma unroll
                for (int nt = 0; nt < NTp; nt++) {
                    acc0[m][nt] = (f4v){0.f, 0.f, 0.f, 0.f};
                    acc1[m][nt] = (f4v){0.f, 0.f, 0.f, 0.f};
                }

#pragma unroll
            for (int ks = 0; ks < KS; ks++) {
#pragma unroll
                for (int m = 0; m < NMAT; m++) {
#pragma unroll
                    for (int nt = 0; nt < NTp; nt++) {
                        s8v bh = lds[(m * NCOMP + 0) * FRp + (nt * KS + ks) * 64 + lane];
                        acc0[m][nt] = __builtin_amdgcn_mfma_f32_16x16x32_bf16(a0h[ks], bh, acc0[m][nt], 0, 0, 0);
                        acc1[m][nt] = __builtin_amdgcn_mfma_f32_16x16x32_bf16(a1h[ks], bh, acc1[m][nt], 0, 0, 0);
                        if (NCOMP == 2) {
                            s8v bl = lds[(m * NCOMP + 1) * FRp + (nt * KS + ks) * 64 + lane];
                            acc0[m][nt] = __builtin_amdgcn_mfma_f32_16x16x32_bf16(a0h[ks], bl, acc0[m][nt], 0, 0, 0);
                            acc1[m][nt] = __builtin_amdgcn_mfma_f32_16x16x32_bf16(a1h[ks], bl, acc1[m][nt], 0, 0, 0);
                            acc0[m][nt] = __builtin_amdgcn_mfma_f32_16x16x32_bf16(a0l[ks], bh, acc0[m][nt], 0, 0, 0);
                            acc1[m][nt] = __builtin_amdgcn_mfma_f32_16x16x32_bf16(a1l[ks], bh, acc1[m][nt], 0, 0, 0);
                        }
                    }
                }
            }

            const int colBase = p * (NOUT / SPLIT);
#pragma unroll
            for (int m = 0; m < NMAT; m++) {
                const bool obf = ((OUTBF_MASK >> m) & 1) != 0;
#pragma unroll
                for (int nt = 0; nt < NTp; nt++) {
                    const int col = colBase + nt * 16 + m16;
                    float bias = 0.f;
                    if (NBIAS >= 1) bias += b0[col];
                    if (NBIAS >= 2) bias += b1[col];
#pragma unroll
                    for (int r = 0; r < 4; r++) {
                        const int gr0 = row0 + q4 * 4 + r;
                        if (gr0 < M) {
                            const float v0 = acc0[m][nt][r] + bias;
                            if (obf)
                                ((unsigned short*)outs[m])[(size_t)gr0 * NOUT + col] = f2bf(v0);
                            else
                                ((float*)outs[m])[(size_t)gr0 * NOUT + col] = v0;
                        }
                        const int gr1 = gr0 + 16;
                        if (gr1 < M && row0 + 16 < M) {
                            const float v1 = acc1[m][nt][r] + bias;
                            if (obf)
                                ((unsigned short*)outs[m])[(size_t)gr1 * NOUT + col] = f2bf(v1);
                            else
                                ((float*)outs[m])[(size_t)gr1 * NOUT + col] = v1;
                        }
                    }
                }
            }
        }
    }
}

// ---------------------------------------------------------------------------
// Fused per-node attention + residual + LayerNorm. One wave per node;
// lane owns dims (2*lane, 2*lane+1); head = lane>>3.
// Q,K f32; V bf16; embeds (residual, in/out) f32. Math f32.
// ---------------------------------------------------------------------------
__global__ __launch_bounds__(256) void agg_k(
    const float* __restrict__ Q, const float* __restrict__ Kt,
    const unsigned short* __restrict__ Vt,
    const int* __restrict__ rowPtr, const int* __restrict__ colIdx,
    const float* __restrict__ ln_s, const float* __restrict__ ln_b,
    float* __restrict__ embeds, int n)
{
    const int node = blockIdx.x * 4 + (threadIdx.x >> 6);
    if (node >= n) return;
    const int lane = threadIdx.x & 63;
    const int d = lane * 2;

    const float2 q = *(const float2*)(Q + (size_t)node * DIM + d);
    const float2 rr = *(const float2*)(embeds + (size_t)node * DIM + d);

    const int e0 = rowPtr[node], e1 = rowPtr[node + 1];
    float acc0 = 0.f, acc1 = 0.f, den = 0.f;
    for (int e = e0; e < e1; e++) {
        const int c = colIdx[e];
        const float2 k = *(const float2*)(Kt + (size_t)c * DIM + d);
        const unsigned int vu = *(const unsigned int*)(Vt + (size_t)c * DIM + d);
        float p = q.x * k.x + q.y * k.y;
        p += __shfl_xor(p, 1);
        p += __shfl_xor(p, 2);
        p += __shfl_xor(p, 4);
        p = fminf(fmaxf(p, -10.f), 10.f);
        const float w = expf(p);
        den += w;
        acc0 += w * bf2f(vu & 0xffffu);
        acc1 += w * bf2f(vu >> 16);
    }
    const float inv = 1.f / (den + 1e-8f);
    const float o0 = acc0 * inv + rr.x;
    const float o1 = acc1 * inv + rr.y;

    float s = o0 + o1, s2 = o0 * o0 + o1 * o1;
#pragma unroll
    for (int m = 1; m < 64; m <<= 1) {
        s  += __shfl_xor(s, m);
        s2 += __shfl_xor(s2, m);
    }
    const float mu = s * (1.f / 128.f);
    const float var = s2 * (1.f / 128.f) - mu * mu;
    const float rs = rsqrtf(var + 1e-6f);
    float2 y;
    y.x = (o0 - mu) * rs * ln_s[d] + ln_b[d];
    y.y = (o1 - mu) * rs * ln_s[d + 1] + ln_b[d + 1];
    *(float2*)(embeds + (size_t)node * DIM + d) = y;
}

// ---------------------------------------------------------------------------
// Launch
// ---------------------------------------------------------------------------
extern "C" void kernel_launch(void* const* d_in, const int* in_sizes, int n_in,
                              void* d_out, int out_size, void* d_ws, size_t ws_size,
                              hipStream_t stream)
{
    const float* x    = (const float*)d_in[0];
    const void*  ei   = d_in[1];
    const float* Wp   = (const float*)d_in[2];
    const float* Wpb  = (const float*)d_in[3];
    const float* Wpos = (const float*)d_in[4];
    const float* q1   = (const float*)d_in[5];
    const float* k1   = (const float*)d_in[6];
    const float* v1   = (const float*)d_in[7];
    const float* l1s  = (const float*)d_in[8];
    const float* l1b  = (const float*)d_in[9];
    const float* q2   = (const float*)d_in[10];
    const float* k2   = (const float*)d_in[11];
    const float* v2   = (const float*)d_in[12];
    const float* l2s  = (const float*)d_in[13];
    const float* l2b  = (const float*)d_in[14];
    const float* invw = (const float*)d_in[15];
    const float* invb = (const float*)d_in[16];

    const int N = in_sizes[0] / 256;   // 50000
    const int E = in_sizes[1] / 2;     // 800000

    char* p = (char*)d_ws;
    auto carve = [&](size_t bytes) -> void* {
        void* r = (void*)p;
        p += (bytes + 255) & ~(size_t)255;
        return r;
    };
    float* embeds = (float*)carve((size_t)N * DIM * 4);
    float* Qb     = (float*)carve((size_t)N * DIM * 4);
    float* Kb     = (float*)carve((size_t)N * DIM * 4);
    unsigned short* Vb = (unsigned short*)carve((size_t)N * DIM * 2);
    int*   deg    = (int*)carve((size_t)N * 4);
    int*   incl   = (int*)carve((size_t)N * 4);
    int*   blkS   = (int*)carve(1024);
    int*   rowPtr = (int*)carve((size_t)(N + 1) * 4);
    int*   cursor = (int*)carve((size_t)N * 4);
    int*   colIdx = (int*)carve((size_t)E * 4);
    int*   rc     = (int*)carve((size_t)2 * E * 4);
    int*   wflag  = (int*)carve(256);
    // wfrag buffers (shorts): sizes = ncomp * Kd * Nd
    unsigned short* wfragP    = (unsigned short*)carve((size_t)2 * 256 * 128 * 2);
    unsigned short* wfragQKV1 = (unsigned short*)carve((size_t)3 * 2 * 128 * 128 * 2);
    unsigned short* wfragQKV2 = (unsigned short*)carve((size_t)3 * 2 * 128 * 128 * 2);
    unsigned short* wfragO    = (unsigned short*)carve((size_t)1 * 128 * 256 * 2);

    const size_t matStride = (size_t)2 * 128 * 128;  // shorts per QKV mat (ncomp=2)

    int* rows = rc;
    int* cols = rc + E;

    const int nb  = (N + 255) / 256;
    const int ebl = (E + 255) / 256;

    // edge_index normalization + CSR build
    detect_width_k<<<1, 256, 0, stream>>>((const unsigned int*)ei, wflag);
    cvt_edges_k<<<(2 * E + 255) / 256, 256, 0, stream>>>(ei, wflag, 2 * E, rc);
    hipMemsetAsync(deg, 0, (size_t)N * 4, stream);
    count_deg_k<<<ebl, 256, 0, stream>>>(rows, E, deg);
    scan1_k<<<nb, 256, 0, stream>>>(deg, N, incl, blkS);
    scan2_k<<<1, 256, 0, stream>>>(blkS, nb);
    scan3_k<<<nb, 256, 0, stream>>>(incl, deg, blkS, N, rowPtr, cursor);
    scatter_k<<<ebl, 256, 0, stream>>>(rows, cols, E, cursor, colIdx);

    // weight fragment prebuild: (W, dst, Kd, Nd, split, ncomp)
    build_wfrag_k<<<32, 256, 0, stream>>>(Wp, wfragP, 256, 128, 4, 2);
    build_wfrag_k<<<16, 256, 0, stream>>>(q1, wfragQKV1 + 0 * matStride, 128, 128, 4, 2);
    build_wfrag_k<<<16, 256, 0, stream>>>(k1, wfragQKV1 + 1 * matStride, 128, 128, 4, 2);
    build_wfrag_k<<<16, 256, 0, stream>>>(v1, wfragQKV1 + 2 * matStride, 128, 128, 4, 2);
    build_wfrag_k<<<16, 256, 0, stream>>>(q2, wfragQKV2 + 0 * matStride, 128, 128, 4, 2);
    build_wfrag_k<<<16, 256, 0, stream>>>(k2, wfragQKV2 + 1 * matStride, 128, 128, 4, 2);
    build_wfrag_k<<<16, 256, 0, stream>>>(v2, wfragQKV2 + 2 * matStride, 128, 128, 4, 2);
    build_wfrag_k<<<16, 256, 0, stream>>>(invw, wfragO, 128, 256, 2, 1);

    // input projection (split-precision): embeds(f32) = x @ W_P + b + pos
    gemm_mfma_k<256, 128, 1, 4, 2, 0, 2><<<256, 512, 0, stream>>>(
        x, wfragP, Wpb, Wpos, embeds, nullptr, nullptr, N);

    // layer 1: fused QKV (split-precision; Q,K f32, V bf16), then attention+LN
    gemm_mfma_k<128, 128, 3, 4, 2, 0b100, 0><<<256, 512, 0, stream>>>(
        embeds, wfragQKV1, nullptr, nullptr, Qb, Kb, Vb, N);
    agg_k<<<(N + 3) / 4, 256, 0, stream>>>(Qb, Kb, Vb, rowPtr, colIdx, l1s, l1b, embeds, N);

    // layer 2
    gemm_mfma_k<128, 128, 3, 4, 2, 0b100, 0><<<256, 512, 0, stream>>>(
        embeds, wfragQKV2, nullptr, nullptr, Qb, Kb, Vb, N);
    agg_k<<<(N + 3) / 4, 256, 0, stream>>>(Qb, Kb, Vb, rowPtr, colIdx, l2s, l2b, embeds, N);

    // output projection (plain bf16 MFMA, linear path): d_out(f32)
    gemm_mfma_k<128, 256, 1, 2, 1, 0, 1><<<256, 512, 0, stream>>>(
        embeds, wfragO, invb, nullptr, d_out, nullptr, nullptr, N);
}

// Round 5
// 552.528 us; speedup vs baseline: 1.3861x; 1.2156x over previous
//
#include <hip/hip_runtime.h>
#include <hip/hip_bf16.h>

#define HEADS 8
#define DIM 128

typedef short s8v __attribute__((ext_vector_type(8)));
typedef float f4v __attribute__((ext_vector_type(4)));

__device__ __forceinline__ float bf2f(unsigned int lo16) {
    union { unsigned int i; float f; } v; v.i = lo16 << 16; return v.f;
}
__device__ __forceinline__ unsigned short f2bf(float f) {
    __hip_bfloat16 h = __float2bfloat16(f);
    return *reinterpret_cast<unsigned short*>(&h);
}
__device__ __forceinline__ int imin(int a, int b) { return a < b ? a : b; }

// ---------------------------------------------------------------------------
// edge_index dtype normalization (int64 vs int32), validated in R2.
// ---------------------------------------------------------------------------
__global__ void detect_width_k(const unsigned int* __restrict__ w, int* __restrict__ flag) {
    __shared__ int cnt;
    if (threadIdx.x == 0) cnt = 0;
    __syncthreads();
    if (w[2 * threadIdx.x + 1] == 0u) atomicAdd(&cnt, 1);
    __syncthreads();
    if (threadIdx.x == 0) flag[0] = (cnt > 192) ? 1 : 0;
}

__global__ void cvt_edges_k(const void* __restrict__ ei, const int* __restrict__ flag,
                            int n2, int* __restrict__ out) {
    int i = blockIdx.x * 256 + threadIdx.x;
    if (i < n2) {
        if (flag[0])
            out[i] = (int)((const long long*)ei)[i];
        else
            out[i] = ((const int*)ei)[i];
    }
}

// ---------------------------------------------------------------------------
// CSR build kernels (validated in R2)
// ---------------------------------------------------------------------------
__global__ void count_deg_k(const int* __restrict__ rows, int E, int* __restrict__ deg) {
    int e = blockIdx.x * 256 + threadIdx.x;
    if (e < E) atomicAdd(&deg[rows[e]], 1);
}

__global__ void scan1_k(const int* __restrict__ deg, int n,
                        int* __restrict__ incl, int* __restrict__ blkSums) {
    __shared__ int s[256];
    int i = blockIdx.x * 256 + threadIdx.x;
    int v = (i < n) ? deg[i] : 0;
    s[threadIdx.x] = v;
    __syncthreads();
    for (int off = 1; off < 256; off <<= 1) {
        int t = (threadIdx.x >= off) ? s[threadIdx.x - off] : 0;
        __syncthreads();
        s[threadIdx.x] += t;
        __syncthreads();
    }
    if (i < n) incl[i] = s[threadIdx.x];
    if (threadIdx.x == 255) blkSums[blockIdx.x] = s[255];
}

__global__ void scan2_k(int* __restrict__ blkSums, int nb) {
    __shared__ int s[256];
    int v = (threadIdx.x < nb) ? blkSums[threadIdx.x] : 0;
    s[threadIdx.x] = v;
    __syncthreads();
    for (int off = 1; off < 256; off <<= 1) {
        int t = (threadIdx.x >= off) ? s[threadIdx.x - off] : 0;
        __syncthreads();
        s[threadIdx.x] += t;
        __syncthreads();
    }
    if (threadIdx.x < nb) blkSums[threadIdx.x] = s[threadIdx.x] - v;
}

__global__ void scan3_k(const int* __restrict__ incl, const int* __restrict__ deg,
                        const int* __restrict__ blkOff, int n,
                        int* __restrict__ rowPtr, int* __restrict__ cursor) {
    int i = blockIdx.x * 256 + threadIdx.x;
    if (i < n) {
        int inc = incl[i] + blkOff[blockIdx.x];
        rowPtr[i + 1] = inc;
        cursor[i] = inc - deg[i];
    }
    if (i == 0) rowPtr[0] = 0;
}

__global__ void scatter_k(const int* __restrict__ rows, const int* __restrict__ cols, int E,
                          int* __restrict__ cursor, int* __restrict__ colIdx) {
    int e = blockIdx.x * 256 + threadIdx.x;
    if (e < E) {
        int pos = atomicAdd(&cursor[rows[e]], 1);
        colIdx[pos] = cols[e];
    }
}

// ---------------------------------------------------------------------------
// Build MFMA B-fragments from f32 W [Kd, Nd]; `split` column phases, `ncomp`
// bf16 components (hi, lo). Frag f = (comp*split + p)*perPhase + (nt*KS+ks)*64
// + lane; element j = W[ks*32 + (lane>>4)*8 + j][p*(Nd/split) + nt*16 + (lane&15)].
// ---------------------------------------------------------------------------
__global__ void build_wfrag_k(const float* __restrict__ W, unsigned short* __restrict__ dst,
                              int Kd, int Nd, int split, int ncomp) {
    int f = blockIdx.x * 256 + threadIdx.x;
    int KS = Kd >> 5;
    int perPhase = (Nd / 16 / split) * KS * 64;
    int total = ncomp * split * perPhase;
    if (f >= total) return;
    int comp = f / (split * perPhase);
    int r1 = f - comp * split * perPhase;
    int p = r1 / perPhase;
    int r = r1 - p * perPhase;
    int nt = r / (KS * 64);
    int r2 = r - nt * KS * 64;
    int ks = r2 >> 6, lane = r2 & 63;
    int n = p * (Nd / split) + nt * 16 + (lane & 15);
    int k0 = ks * 32 + (lane >> 4) * 8;
    unsigned short tmp[8];
#pragma unroll
    for (int j = 0; j < 8; j++) {
        float w = W[(size_t)(k0 + j) * Nd + n];
        unsigned short hi = f2bf(w);
        tmp[j] = (comp == 0) ? hi : f2bf(w - bf2f(hi));
    }
#pragma unroll
    for (int j = 0; j < 8; j++) dst[(size_t)f * 8 + j] = tmp[j];
}

// ---------------------------------------------------------------------------
// Input projection: trunk planes = x(f32)[M,256] @ W_P + Wpb + Wpos.
// grid (196, 2): blockIdx.y = column phase (64 cols each). 512 thr = 8 waves,
// one 32-row pair per wave. B hi/lo in LDS; A converted to hi/lo on the fly.
// Split-bf16: Ah*Bh + Ah*Bl + Al*Bh.
// ---------------------------------------------------------------------------
__global__ __launch_bounds__(512) void proj_k(
    const float* __restrict__ A, const unsigned short* __restrict__ wfrag,
    const float* __restrict__ b0, const float* __restrict__ b1,
    unsigned short* __restrict__ ehi, unsigned short* __restrict__ elo, int M)
{
    constexpr int KD = 256, KS = 8, NTp = 4;
    constexpr int FRp = NTp * KS * 64;  // 2048
    __shared__ s8v lds[2 * FRp];        // 64 KB

    const int tid = threadIdx.x;
    const int lane = tid & 63;
    const int m16 = lane & 15, q4 = lane >> 4;
    const int phase = blockIdx.y;
    const int pairIdx = blockIdx.x * 8 + (tid >> 6);
    const int nPairs = (M + 31) >> 5;

    for (int idx = tid; idx < 2 * FRp; idx += 512) {
        int comp = idx / FRp, r = idx - comp * FRp;
        lds[idx] = *(const s8v*)(wfrag + ((size_t)((comp * 2 + phase) * FRp) + r) * 8);
    }
    __syncthreads();
    if (pairIdx >= nPairs) return;

    const int row0 = pairIdx * 32;
    const int rA0 = imin(row0 + m16, M - 1);
    const int rA1 = imin(row0 + 16 + m16, M - 1);

    f4v acc0[NTp], acc1[NTp];
#pragma unroll
    for (int nt = 0; nt < NTp; nt++) { acc0[nt] = (f4v){0,0,0,0}; acc1[nt] = (f4v){0,0,0,0}; }

    for (int ks = 0; ks < KS; ks++) {
        const float* pa0 = A + (size_t)rA0 * KD + ks * 32 + q4 * 8;
        const float* pa1 = A + (size_t)rA1 * KD + ks * 32 + q4 * 8;
        s8v a0h, a0l, a1h, a1l;
#pragma unroll
        for (int j = 0; j < 8; j++) {
            float x0 = pa0[j], x1 = pa1[j];
            unsigned short h0 = f2bf(x0), h1 = f2bf(x1);
            a0h[j] = (short)h0; a1h[j] = (short)h1;
            a0l[j] = (short)f2bf(x0 - bf2f(h0));
            a1l[j] = (short)f2bf(x1 - bf2f(h1));
        }
#pragma unroll
        for (int nt = 0; nt < NTp; nt++) {
            s8v bh = lds[0 * FRp + (nt * KS + ks) * 64 + lane];
            s8v bl = lds[1 * FRp + (nt * KS + ks) * 64 + lane];
            acc0[nt] = __builtin_amdgcn_mfma_f32_16x16x32_bf16(a0h, bh, acc0[nt], 0, 0, 0);
            acc0[nt] = __builtin_amdgcn_mfma_f32_16x16x32_bf16(a0h, bl, acc0[nt], 0, 0, 0);
            acc0[nt] = __builtin_amdgcn_mfma_f32_16x16x32_bf16(a0l, bh, acc0[nt], 0, 0, 0);
            acc1[nt] = __builtin_amdgcn_mfma_f32_16x16x32_bf16(a1h, bh, acc1[nt], 0, 0, 0);
            acc1[nt] = __builtin_amdgcn_mfma_f32_16x16x32_bf16(a1h, bl, acc1[nt], 0, 0, 0);
            acc1[nt] = __builtin_amdgcn_mfma_f32_16x16x32_bf16(a1l, bh, acc1[nt], 0, 0, 0);
        }
    }

#pragma unroll
    for (int nt = 0; nt < NTp; nt++) {
        const int col = phase * 64 + nt * 16 + m16;
        const float bias = b0[col] + b1[col];
#pragma unroll
        for (int r = 0; r < 4; r++) {
            const int gr0 = row0 + q4 * 4 + r;
            if (gr0 < M) {
                float v = acc0[nt][r] + bias;
                unsigned short h = f2bf(v);
                ehi[(size_t)gr0 * DIM + col] = h;
                elo[(size_t)gr0 * DIM + col] = f2bf(v - bf2f(h));
            }
            const int gr1 = gr0 + 16;
            if (gr1 < M && row0 + 16 < M) {
                float v = acc1[nt][r] + bias;
                unsigned short h = f2bf(v);
                ehi[(size_t)gr1 * DIM + col] = h;
                elo[(size_t)gr1 * DIM + col] = f2bf(v - bf2f(h));
            }
        }
    }
}

// ---------------------------------------------------------------------------
// Fused QKV: A = trunk planes (hi/lo bf16). Q = split-precision f32 out;
// K,V = bf16 interleaved KV[M][256] (K cols 0..127, V cols 128..255).
// B slots in LDS: {Qh,Ql,Kh,Kl,Vh} (V hi-only). grid (196,2).
// ---------------------------------------------------------------------------
__global__ __launch_bounds__(512) void qkv_k(
    const unsigned short* __restrict__ ehi, const unsigned short* __restrict__ elo,
    const unsigned short* __restrict__ wfrag,
    float* __restrict__ Qb, unsigned short* __restrict__ KVb, int M)
{
    constexpr int KS = 4, NTp = 4;
    constexpr int FRp = NTp * KS * 64;     // 1024
    constexpr int MATFR = 4 * FRp;         // frags per mat in wfrag (2 comp x 2 phase)
    __shared__ s8v lds[5 * FRp];           // 80 KB

    const int tid = threadIdx.x;
    const int lane = tid & 63;
    const int m16 = lane & 15, q4 = lane >> 4;
    const int phase = blockIdx.y;
    const int pairIdx = blockIdx.x * 8 + (tid >> 6);
    const int nPairs = (M + 31) >> 5;

    // slot s: mat {0,0,1,1,2}, comp {0,1,0,1,0}
    for (int idx = tid; idx < 5 * FRp; idx += 512) {
        int s = idx / FRp, r = idx - s * FRp;
        int mat = (s < 2) ? 0 : (s < 4) ? 1 : 2;
        int comp = (s < 4) ? (s & 1) : 0;
        lds[idx] = *(const s8v*)(wfrag + ((size_t)mat * MATFR + (comp * 2 + phase) * FRp + r) * 8);
    }
    __syncthreads();
    if (pairIdx >= nPairs) return;

    const int row0 = pairIdx * 32;
    const int rA0 = imin(row0 + m16, M - 1);
    const int rA1 = imin(row0 + 16 + m16, M - 1);

    s8v a0h[KS], a0l[KS], a1h[KS], a1l[KS];
#pragma unroll
    for (int ks = 0; ks < KS; ks++) {
        a0h[ks] = *(const s8v*)(ehi + (size_t)rA0 * DIM + ks * 32 + q4 * 8);
        a0l[ks] = *(const s8v*)(elo + (size_t)rA0 * DIM + ks * 32 + q4 * 8);
        a1h[ks] = *(const s8v*)(ehi + (size_t)rA1 * DIM + ks * 32 + q4 * 8);
        a1l[ks] = *(const s8v*)(elo + (size_t)rA1 * DIM + ks * 32 + q4 * 8);
    }

    f4v aQ0[NTp], aQ1[NTp], aK0[NTp], aK1[NTp], aV0[NTp], aV1[NTp];
#pragma unroll
    for (int nt = 0; nt < NTp; nt++) {
        aQ0[nt] = (f4v){0,0,0,0}; aQ1[nt] = (f4v){0,0,0,0};
        aK0[nt] = (f4v){0,0,0,0}; aK1[nt] = (f4v){0,0,0,0};
        aV0[nt] = (f4v){0,0,0,0}; aV1[nt] = (f4v){0,0,0,0};
    }

#pragma unroll
    for (int ks = 0; ks < KS; ks++) {
#pragma unroll
        for (int nt = 0; nt < NTp; nt++) {
            const int fi = (nt * KS + ks) * 64 + lane;
            s8v qh = lds[0 * FRp + fi], ql = lds[1 * FRp + fi];
            s8v kh = lds[2 * FRp + fi], kl = lds[3 * FRp + fi];
            s8v vh = lds[4 * FRp + fi];
            aQ0[nt] = __builtin_amdgcn_mfma_f32_16x16x32_bf16(a0h[ks], qh, aQ0[nt], 0, 0, 0);
            aQ0[nt] = __builtin_amdgcn_mfma_f32_16x16x32_bf16(a0h[ks], ql, aQ0[nt], 0, 0, 0);
            aQ0[nt] = __builtin_amdgcn_mfma_f32_16x16x32_bf16(a0l[ks], qh, aQ0[nt], 0, 0, 0);
            aQ1[nt] = __builtin_amdgcn_mfma_f32_16x16x32_bf16(a1h[ks], qh, aQ1[nt], 0, 0, 0);
            aQ1[nt] = __builtin_amdgcn_mfma_f32_16x16x32_bf16(a1h[ks], ql, aQ1[nt], 0, 0, 0);
            aQ1[nt] = __builtin_amdgcn_mfma_f32_16x16x32_bf16(a1l[ks], qh, aQ1[nt], 0, 0, 0);
            aK0[nt] = __builtin_amdgcn_mfma_f32_16x16x32_bf16(a0h[ks], kh, aK0[nt], 0, 0, 0);
            aK0[nt] = __builtin_amdgcn_mfma_f32_16x16x32_bf16(a0h[ks], kl, aK0[nt], 0, 0, 0);
            aK0[nt] = __builtin_amdgcn_mfma_f32_16x16x32_bf16(a0l[ks], kh, aK0[nt], 0, 0, 0);
            aK1[nt] = __builtin_amdgcn_mfma_f32_16x16x32_bf16(a1h[ks], kh, aK1[nt], 0, 0, 0);
            aK1[nt] = __builtin_amdgcn_mfma_f32_16x16x32_bf16(a1h[ks], kl, aK1[nt], 0, 0, 0);
            aK1[nt] = __builtin_amdgcn_mfma_f32_16x16x32_bf16(a1l[ks], kh, aK1[nt], 0, 0, 0);
            aV0[nt] = __builtin_amdgcn_mfma_f32_16x16x32_bf16(a0h[ks], vh, aV0[nt], 0, 0, 0);
            aV0[nt] = __builtin_amdgcn_mfma_f32_16x16x32_bf16(a0l[ks], vh, aV0[nt], 0, 0, 0);
            aV1[nt] = __builtin_amdgcn_mfma_f32_16x16x32_bf16(a1h[ks], vh, aV1[nt], 0, 0, 0);
            aV1[nt] = __builtin_amdgcn_mfma_f32_16x16x32_bf16(a1l[ks], vh, aV1[nt], 0, 0, 0);
        }
    }

#pragma unroll
    for (int nt = 0; nt < NTp; nt++) {
        const int col = phase * 64 + nt * 16 + m16;
#pragma unroll
        for (int r = 0; r < 4; r++) {
            const int gr0 = row0 + q4 * 4 + r;
            if (gr0 < M) {
                Qb[(size_t)gr0 * DIM + col] = aQ0[nt][r];
                KVb[(size_t)gr0 * 256 + col] = f2bf(aK0[nt][r]);
                KVb[(size_t)gr0 * 256 + 128 + col] = f2bf(aV0[nt][r]);
            }
            const int gr1 = gr0 + 16;
            if (gr1 < M && row0 + 16 < M) {
                Qb[(size_t)gr1 * DIM + col] = aQ1[nt][r];
                KVb[(size_t)gr1 * 256 + col] = f2bf(aK1[nt][r]);
                KVb[(size_t)gr1 * 256 + 128 + col] = f2bf(aV1[nt][r]);
            }
        }
    }
}

// ---------------------------------------------------------------------------
// Output projection: d_out(f32)[M,256] = trunk @ inv_w + inv_b.
// A = planes, 2-term (Ah*B + Al*B). grid (196,2), 128 cols per phase.
// ---------------------------------------------------------------------------
__global__ __launch_bounds__(512) void outproj_k(
    const unsigned short* __restrict__ ehi, const unsigned short* __restrict__ elo,
    const unsigned short* __restrict__ wfrag, const float* __restrict__ b0,
    float* __restrict__ Out, int M)
{
    constexpr int KS = 4, NTp = 8, NOUT = 256;
    constexpr int FRp = NTp * KS * 64;  // 2048
    __shared__ s8v lds[FRp];            // 32 KB

    const int tid = threadIdx.x;
    const int lane = tid & 63;
    const int m16 = lane & 15, q4 = lane >> 4;
    const int phase = blockIdx.y;
    const int pairIdx = blockIdx.x * 8 + (tid >> 6);
    const int nPairs = (M + 31) >> 5;

    for (int idx = tid; idx < FRp; idx += 512)
        lds[idx] = *(const s8v*)(wfrag + ((size_t)phase * FRp + idx) * 8);
    __syncthreads();
    if (pairIdx >= nPairs) return;

    const int row0 = pairIdx * 32;
    const int rA0 = imin(row0 + m16, M - 1);
    const int rA1 = imin(row0 + 16 + m16, M - 1);

    s8v a0h[KS], a0l[KS], a1h[KS], a1l[KS];
#pragma unroll
    for (int ks = 0; ks < KS; ks++) {
        a0h[ks] = *(const s8v*)(ehi + (size_t)rA0 * DIM + ks * 32 + q4 * 8);
        a0l[ks] = *(const s8v*)(elo + (size_t)rA0 * DIM + ks * 32 + q4 * 8);
        a1h[ks] = *(const s8v*)(ehi + (size_t)rA1 * DIM + ks * 32 + q4 * 8);
        a1l[ks] = *(const s8v*)(elo + (size_t)rA1 * DIM + ks * 32 + q4 * 8);
    }

    f4v acc0[NTp], acc1[NTp];
#pragma unroll
    for (int nt = 0; nt < NTp; nt++) { acc0[nt] = (f4v){0,0,0,0}; acc1[nt] = (f4v){0,0,0,0}; }

#pragma unroll
    for (int ks = 0; ks < KS; ks++) {
#pragma unroll
        for (int nt = 0; nt < NTp; nt++) {
            s8v b = lds[(nt * KS + ks) * 64 + lane];
            acc0[nt] = __builtin_amdgcn_mfma_f32_16x16x32_bf16(a0h[ks], b, acc0[nt], 0, 0, 0);
            acc0[nt] = __builtin_amdgcn_mfma_f32_16x16x32_bf16(a0l[ks], b, acc0[nt], 0, 0, 0);
            acc1[nt] = __builtin_amdgcn_mfma_f32_16x16x32_bf16(a1h[ks], b, acc1[nt], 0, 0, 0);
            acc1[nt] = __builtin_amdgcn_mfma_f32_16x16x32_bf16(a1l[ks], b, acc1[nt], 0, 0, 0);
        }
    }

#pragma unroll
    for (int nt = 0; nt < NTp; nt++) {
        const int col = phase * 128 + nt * 16 + m16;
        const float bias = b0[col];
#pragma unroll
        for (int r = 0; r < 4; r++) {
            const int gr0 = row0 + q4 * 4 + r;
            if (gr0 < M) Out[(size_t)gr0 * NOUT + col] = acc0[nt][r] + bias;
            const int gr1 = gr0 + 16;
            if (gr1 < M && row0 + 16 < M) Out[(size_t)gr1 * NOUT + col] = acc1[nt][r] + bias;
        }
    }
}

// ---------------------------------------------------------------------------
// Fused attention + residual + LayerNorm. One wave per node; lane owns dims
// (2*lane, 2*lane+1); head = lane>>3. Q f32; KV interleaved bf16; trunk
// residual read/write = hi/lo bf16 planes. Edge loop software-pipelined.
// ---------------------------------------------------------------------------
__global__ __launch_bounds__(256) void agg_k(
    const float* __restrict__ Q, const unsigned short* __restrict__ KV,
    const int* __restrict__ rowPtr, const int* __restrict__ colIdx,
    const float* __restrict__ ln_s, const float* __restrict__ ln_b,
    unsigned short* __restrict__ ehi, unsigned short* __restrict__ elo, int n)
{
    const int node = blockIdx.x * 4 + (threadIdx.x >> 6);
    if (node >= n) return;
    const int lane = threadIdx.x & 63;
    const int d = lane * 2;

    const float2 q = *(const float2*)(Q + (size_t)node * DIM + d);
    const unsigned int rh = *(const unsigned int*)(ehi + (size_t)node * DIM + d);
    const unsigned int rl = *(const unsigned int*)(elo + (size_t)node * DIM + d);
    const float r0 = bf2f(rh & 0xffffu) + bf2f(rl & 0xffffu);
    const float r1 = bf2f(rh >> 16) + bf2f(rl >> 16);

    const int e0 = rowPtr[node], e1 = rowPtr[node + 1];
    float acc0 = 0.f, acc1 = 0.f, den = 0.f;

    if (e1 > e0) {
        int c = colIdx[e0];
        unsigned int ku = *(const unsigned int*)(KV + (size_t)c * 256 + d);
        unsigned int vu = *(const unsigned int*)(KV + (size_t)c * 256 + 128 + d);
        for (int e = e0; e < e1; e++) {
            unsigned int kuc = ku, vuc = vu;
            if (e + 1 < e1) {
                const int cn = colIdx[e + 1];
                ku = *(const unsigned int*)(KV + (size_t)cn * 256 + d);
                vu = *(const unsigned int*)(KV + (size_t)cn * 256 + 128 + d);
            }
            float p = q.x * bf2f(kuc & 0xffffu) + q.y * bf2f(kuc >> 16);
            p += __shfl_xor(p, 1);
            p += __shfl_xor(p, 2);
            p += __shfl_xor(p, 4);
            p = fminf(fmaxf(p, -10.f), 10.f);
            const float w = expf(p);
            den += w;
            acc0 += w * bf2f(vuc & 0xffffu);
            acc1 += w * bf2f(vuc >> 16);
        }
    }
    const float inv = 1.f / (den + 1e-8f);
    const float o0 = acc0 * inv + r0;
    const float o1 = acc1 * inv + r1;

    float s = o0 + o1, s2 = o0 * o0 + o1 * o1;
#pragma unroll
    for (int m = 1; m < 64; m <<= 1) {
        s  += __shfl_xor(s, m);
        s2 += __shfl_xor(s2, m);
    }
    const float mu = s * (1.f / 128.f);
    const float var = s2 * (1.f / 128.f) - mu * mu;
    const float rs = rsqrtf(var + 1e-6f);
    const float y0 = (o0 - mu) * rs * ln_s[d] + ln_b[d];
    const float y1 = (o1 - mu) * rs * ln_s[d + 1] + ln_b[d + 1];
    const unsigned short h0 = f2bf(y0), h1 = f2bf(y1);
    const unsigned short l0 = f2bf(y0 - bf2f(h0)), l1 = f2bf(y1 - bf2f(h1));
    *(unsigned int*)(ehi + (size_t)node * DIM + d) = (unsigned int)h0 | ((unsigned int)h1 << 16);
    *(unsigned int*)(elo + (size_t)node * DIM + d) = (unsigned int)l0 | ((unsigned int)l1 << 16);
}

// ---------------------------------------------------------------------------
// Launch
// ---------------------------------------------------------------------------
extern "C" void kernel_launch(void* const* d_in, const int* in_sizes, int n_in,
                              void* d_out, int out_size, void* d_ws, size_t ws_size,
                              hipStream_t stream)
{
    const float* x    = (const float*)d_in[0];
    const void*  ei   = d_in[1];
    const float* Wp   = (const float*)d_in[2];
    const float* Wpb  = (const float*)d_in[3];
    const float* Wpos = (const float*)d_in[4];
    const float* q1   = (const float*)d_in[5];
    const float* k1   = (const float*)d_in[6];
    const float* v1   = (const float*)d_in[7];
    const float* l1s  = (const float*)d_in[8];
    const float* l1b  = (const float*)d_in[9];
    const float* q2   = (const float*)d_in[10];
    const float* k2   = (const float*)d_in[11];
    const float* v2   = (const float*)d_in[12];
    const float* l2s  = (const float*)d_in[13];
    const float* l2b  = (const float*)d_in[14];
    const float* invw = (const float*)d_in[15];
    const float* invb = (const float*)d_in[16];

    const int N = in_sizes[0] / 256;   // 50000
    const int E = in_sizes[1] / 2;     // 800000

    char* p = (char*)d_ws;
    auto carve = [&](size_t bytes) -> void* {
        void* r = (void*)p;
        p += (bytes + 255) & ~(size_t)255;
        return r;
    };
    unsigned short* ehi = (unsigned short*)carve((size_t)N * DIM * 2);
    unsigned short* elo = (unsigned short*)carve((size_t)N * DIM * 2);
    float*          Qb  = (float*)carve((size_t)N * DIM * 4);
    unsigned short* KVb = (unsigned short*)carve((size_t)N * 256 * 2);
    int*   deg    = (int*)carve((size_t)N * 4);
    int*   incl   = (int*)carve((size_t)N * 4);
    int*   blkS   = (int*)carve(1024);
    int*   rowPtr = (int*)carve((size_t)(N + 1) * 4);
    int*   cursor = (int*)carve((size_t)N * 4);
    int*   colIdx = (int*)carve((size_t)E * 4);
    int*   rc     = (int*)carve((size_t)2 * E * 4);
    int*   wflag  = (int*)carve(256);
    unsigned short* wfragP    = (unsigned short*)carve((size_t)2 * 256 * 128 * 2);
    unsigned short* wfragQKV1 = (unsigned short*)carve((size_t)3 * 2 * 128 * 128 * 2);
    unsigned short* wfragQKV2 = (unsigned short*)carve((size_t)3 * 2 * 128 * 128 * 2);
    unsigned short* wfragO    = (unsigned short*)carve((size_t)128 * 256 * 2);

    const size_t matStride = (size_t)2 * 128 * 128;  // shorts per QKV mat

    int* rows = rc;
    int* cols = rc + E;

    const int nb  = (N + 255) / 256;
    const int ebl = (E + 255) / 256;
    const int nPairs = (N + 31) / 32;
    const dim3 ggrid((nPairs + 7) / 8, 2);

    // edge_index normalization + CSR build
    detect_width_k<<<1, 256, 0, stream>>>((const unsigned int*)ei, wflag);
    cvt_edges_k<<<(2 * E + 255) / 256, 256, 0, stream>>>(ei, wflag, 2 * E, rc);
    hipMemsetAsync(deg, 0, (size_t)N * 4, stream);
    count_deg_k<<<ebl, 256, 0, stream>>>(rows, E, deg);
    scan1_k<<<nb, 256, 0, stream>>>(deg, N, incl, blkS);
    scan2_k<<<1, 256, 0, stream>>>(blkS, nb);
    scan3_k<<<nb, 256, 0, stream>>>(incl, deg, blkS, N, rowPtr, cursor);
    scatter_k<<<ebl, 256, 0, stream>>>(rows, cols, E, cursor, colIdx);

    // weight fragment prebuild: (W, dst, Kd, Nd, split, ncomp)
    build_wfrag_k<<<32, 256, 0, stream>>>(Wp, wfragP, 256, 128, 2, 2);
    build_wfrag_k<<<16, 256, 0, stream>>>(q1, wfragQKV1 + 0 * matStride, 128, 128, 2, 2);
    build_wfrag_k<<<16, 256, 0, stream>>>(k1, wfragQKV1 + 1 * matStride, 128, 128, 2, 2);
    build_wfrag_k<<<16, 256, 0, stream>>>(v1, wfragQKV1 + 2 * matStride, 128, 128, 2, 2);
    build_wfrag_k<<<16, 256, 0, stream>>>(q2, wfragQKV2 + 0 * matStride, 128, 128, 2, 2);
    build_wfrag_k<<<16, 256, 0, stream>>>(k2, wfragQKV2 + 1 * matStride, 128, 128, 2, 2);
    build_wfrag_k<<<16, 256, 0, stream>>>(v2, wfragQKV2 + 2 * matStride, 128, 128, 2, 2);
    build_wfrag_k<<<16, 256, 0, stream>>>(invw, wfragO, 128, 256, 2, 1);

    // input projection -> trunk planes
    proj_k<<<ggrid, 512, 0, stream>>>(x, wfragP, Wpb, Wpos, ehi, elo, N);

    // layer 1
    qkv_k<<<ggrid, 512, 0, stream>>>(ehi, elo, wfragQKV1, Qb, KVb, N);
    agg_k<<<(N + 3) / 4, 256, 0, stream>>>(Qb, KVb, rowPtr, colIdx, l1s, l1b, ehi, elo, N);

    // layer 2
    qkv_k<<<ggrid, 512, 0, stream>>>(ehi, elo, wfragQKV2, Qb, KVb, N);
    agg_k<<<(N + 3) / 4, 256, 0, stream>>>(Qb, KVb, rowPtr, colIdx, l2s, l2b, ehi, elo, N);

    // output projection
    outproj_k<<<ggrid, 512, 0, stream>>>(ehi, elo, wfragO, invb, (float*)d_out, N);
}

// Round 6
// 502.022 us; speedup vs baseline: 1.5255x; 1.1006x over previous
//
#include <hip/hip_runtime.h>
#include <hip/hip_bf16.h>

#define HEADS 8
#define DIM 128

typedef short s8v __attribute__((ext_vector_type(8)));
typedef float f4v __attribute__((ext_vector_type(4)));

__device__ __forceinline__ float bf2f(unsigned int lo16) {
    union { unsigned int i; float f; } v; v.i = lo16 << 16; return v.f;
}
__device__ __forceinline__ unsigned short f2bf(float f) {
    __hip_bfloat16 h = __float2bfloat16(f);
    return *reinterpret_cast<unsigned short*>(&h);
}
__device__ __forceinline__ int imin(int a, int b) { return a < b ? a : b; }

// ---------------------------------------------------------------------------
// Fused setup: per-block dtype sniff (int64 vs int32) + edge convert + degree
// count. Every block redundantly sniffs the first 2 KB (validated logic, R2).
// ---------------------------------------------------------------------------
__global__ __launch_bounds__(256) void setup_k(const void* __restrict__ ei, int n2, int E,
                                               int* __restrict__ out, int* __restrict__ deg) {
    __shared__ int cnt;
    const unsigned int* w = (const unsigned int*)ei;
    if (threadIdx.x == 0) cnt = 0;
    __syncthreads();
    if (w[2 * threadIdx.x + 1] == 0u) atomicAdd(&cnt, 1);
    __syncthreads();
    const bool is64 = cnt > 192;
    int i = blockIdx.x * 256 + threadIdx.x;
    if (i < n2) {
        int v = is64 ? (int)((const long long*)ei)[i] : ((const int*)ei)[i];
        out[i] = v;
        if (i < E) atomicAdd(&deg[v], 1);   // rows half
    }
}

// ---------------------------------------------------------------------------
// CSR scan + scatter (validated in R2)
// ---------------------------------------------------------------------------
__global__ void scan1_k(const int* __restrict__ deg, int n,
                        int* __restrict__ incl, int* __restrict__ blkSums) {
    __shared__ int s[256];
    int i = blockIdx.x * 256 + threadIdx.x;
    int v = (i < n) ? deg[i] : 0;
    s[threadIdx.x] = v;
    __syncthreads();
    for (int off = 1; off < 256; off <<= 1) {
        int t = (threadIdx.x >= off) ? s[threadIdx.x - off] : 0;
        __syncthreads();
        s[threadIdx.x] += t;
        __syncthreads();
    }
    if (i < n) incl[i] = s[threadIdx.x];
    if (threadIdx.x == 255) blkSums[blockIdx.x] = s[255];
}

__global__ void scan2_k(int* __restrict__ blkSums, int nb) {
    __shared__ int s[256];
    int v = (threadIdx.x < nb) ? blkSums[threadIdx.x] : 0;
    s[threadIdx.x] = v;
    __syncthreads();
    for (int off = 1; off < 256; off <<= 1) {
        int t = (threadIdx.x >= off) ? s[threadIdx.x - off] : 0;
        __syncthreads();
        s[threadIdx.x] += t;
        __syncthreads();
    }
    if (threadIdx.x < nb) blkSums[threadIdx.x] = s[threadIdx.x] - v;
}

__global__ void scan3_k(const int* __restrict__ incl, const int* __restrict__ deg,
                        const int* __restrict__ blkOff, int n,
                        int* __restrict__ rowPtr, int* __restrict__ cursor) {
    int i = blockIdx.x * 256 + threadIdx.x;
    if (i < n) {
        int inc = incl[i] + blkOff[blockIdx.x];
        rowPtr[i + 1] = inc;
        cursor[i] = inc - deg[i];
    }
    if (i == 0) rowPtr[0] = 0;
}

__global__ void scatter_k(const int* __restrict__ rows, const int* __restrict__ cols, int E,
                          int* __restrict__ cursor, int* __restrict__ colIdx) {
    int e = blockIdx.x * 256 + threadIdx.x;
    if (e < E) {
        int pos = atomicAdd(&cursor[rows[e]], 1);
        colIdx[pos] = cols[e];
    }
}

// ---------------------------------------------------------------------------
// All weight-fragment builds in ONE kernel; job table by blockIdx.
// Frag f = (comp*split + p)*perPhase + (nt*KS + ks)*64 + lane; element j =
// W[ks*32 + (lane>>4)*8 + j][p*(Nd/split) + nt*16 + (lane&15)]. hi/lo bf16.
// ---------------------------------------------------------------------------
__global__ __launch_bounds__(256) void build_all_wfrag_k(
    const float* __restrict__ Wp, const float* __restrict__ q1, const float* __restrict__ k1,
    const float* __restrict__ v1, const float* __restrict__ q2, const float* __restrict__ k2,
    const float* __restrict__ v2, const float* __restrict__ invw,
    unsigned short* __restrict__ wfragP, unsigned short* __restrict__ wfragQKV1,
    unsigned short* __restrict__ wfragQKV2, unsigned short* __restrict__ wfragO)
{
    const int b = blockIdx.x;
    const float* W; unsigned short* dst; int Kd, Nd, ncomp, fb;
    const int split = 2;
    if (b < 32) { W = Wp; dst = wfragP; Kd = 256; Nd = 128; ncomp = 2; fb = b; }
    else if (b < 128) {
        int j = (b - 32) >> 4, r = (b - 32) & 15;
        const float* ws[6] = { q1, k1, v1, q2, k2, v2 };
        W = ws[j];
        dst = ((j < 3) ? wfragQKV1 : wfragQKV2) + (size_t)(j % 3) * 2 * 128 * 128;
        Kd = 128; Nd = 128; ncomp = 2; fb = r;
    } else { W = invw; dst = wfragO; Kd = 128; Nd = 256; ncomp = 1; fb = b - 128; }

    int f = fb * 256 + threadIdx.x;
    int KS = Kd >> 5;
    int perPhase = (Nd / 16 / split) * KS * 64;
    if (f >= ncomp * split * perPhase) return;
    int comp = f / (split * perPhase);
    int r1 = f - comp * split * perPhase;
    int p = r1 / perPhase;
    int r = r1 - p * perPhase;
    int nt = r / (KS * 64);
    int r2 = r - nt * KS * 64;
    int ks = r2 >> 6, lane = r2 & 63;
    int n = p * (Nd / split) + nt * 16 + (lane & 15);
    int k0 = ks * 32 + (lane >> 4) * 8;
    unsigned short tmp[8];
#pragma unroll
    for (int j = 0; j < 8; j++) {
        float w = W[(size_t)(k0 + j) * Nd + n];
        unsigned short hi = f2bf(w);
        tmp[j] = (comp == 0) ? hi : f2bf(w - bf2f(hi));
    }
#pragma unroll
    for (int j = 0; j < 8; j++) dst[(size_t)f * 8 + j] = tmp[j];
}

// ---------------------------------------------------------------------------
// Input projection (LDS-free): trunk planes = x(f32)[M,256] @ W_P + b + pos.
// grid (391,2): blockIdx.y = 64-col phase. 256 thr = 4 waves, 1 row-pair each.
// B-frags read wave-coalesced from global (L2-resident). Ah*Bh+Ah*Bl+Al*Bh.
// ---------------------------------------------------------------------------
__global__ __launch_bounds__(256) void proj_k(
    const float* __restrict__ A, const unsigned short* __restrict__ wfrag,
    const float* __restrict__ b0, const float* __restrict__ b1,
    unsigned short* __restrict__ ehi, unsigned short* __restrict__ elo, int M)
{
    constexpr int KD = 256, KS = 8, NTp = 4;
    constexpr int FRp = NTp * KS * 64;  // 2048
    const int lane = threadIdx.x & 63;
    const int m16 = lane & 15, q4 = lane >> 4;
    const int phase = blockIdx.y;
    const int pairIdx = blockIdx.x * 4 + (threadIdx.x >> 6);
    const int nPairs = (M + 31) >> 5;
    if (pairIdx >= nPairs) return;

    const int row0 = pairIdx * 32;
    const int rA0 = imin(row0 + m16, M - 1);
    const int rA1 = imin(row0 + 16 + m16, M - 1);

    f4v acc0[NTp], acc1[NTp];
#pragma unroll
    for (int nt = 0; nt < NTp; nt++) { acc0[nt] = (f4v){0,0,0,0}; acc1[nt] = (f4v){0,0,0,0}; }

    for (int ks = 0; ks < KS; ks++) {
        const f4v* pa0 = (const f4v*)(A + (size_t)rA0 * KD + ks * 32 + q4 * 8);
        const f4v* pa1 = (const f4v*)(A + (size_t)rA1 * KD + ks * 32 + q4 * 8);
        f4v xa = pa0[0], xb = pa0[1], ya = pa1[0], yb = pa1[1];
        s8v a0h, a0l, a1h, a1l;
#pragma unroll
        for (int j = 0; j < 4; j++) {
            unsigned short h;
            h = f2bf(xa[j]); a0h[j] = (short)h; a0l[j] = (short)f2bf(xa[j] - bf2f(h));
            h = f2bf(xb[j]); a0h[4 + j] = (short)h; a0l[4 + j] = (short)f2bf(xb[j] - bf2f(h));
            h = f2bf(ya[j]); a1h[j] = (short)h; a1l[j] = (short)f2bf(ya[j] - bf2f(h));
            h = f2bf(yb[j]); a1h[4 + j] = (short)h; a1l[4 + j] = (short)f2bf(yb[j] - bf2f(h));
        }
#pragma unroll
        for (int nt = 0; nt < NTp; nt++) {
            const size_t fi = ((size_t)(nt * KS + ks) * 64 + lane) * 8;
            s8v bh = *(const s8v*)(wfrag + ((size_t)(0 * 2 + phase) * FRp) * 8 + fi);
            s8v bl = *(const s8v*)(wfrag + ((size_t)(1 * 2 + phase) * FRp) * 8 + fi);
            acc0[nt] = __builtin_amdgcn_mfma_f32_16x16x32_bf16(a0h, bh, acc0[nt], 0, 0, 0);
            acc0[nt] = __builtin_amdgcn_mfma_f32_16x16x32_bf16(a0h, bl, acc0[nt], 0, 0, 0);
            acc0[nt] = __builtin_amdgcn_mfma_f32_16x16x32_bf16(a0l, bh, acc0[nt], 0, 0, 0);
            acc1[nt] = __builtin_amdgcn_mfma_f32_16x16x32_bf16(a1h, bh, acc1[nt], 0, 0, 0);
            acc1[nt] = __builtin_amdgcn_mfma_f32_16x16x32_bf16(a1h, bl, acc1[nt], 0, 0, 0);
            acc1[nt] = __builtin_amdgcn_mfma_f32_16x16x32_bf16(a1l, bh, acc1[nt], 0, 0, 0);
        }
    }

#pragma unroll
    for (int nt = 0; nt < NTp; nt++) {
        const int col = phase * 64 + nt * 16 + m16;
        const float bias = b0[col] + b1[col];
#pragma unroll
        for (int r = 0; r < 4; r++) {
            const int gr0 = row0 + q4 * 4 + r;
            if (gr0 < M) {
                float v = acc0[nt][r] + bias;
                unsigned short h = f2bf(v);
                ehi[(size_t)gr0 * DIM + col] = h;
                elo[(size_t)gr0 * DIM + col] = f2bf(v - bf2f(h));
            }
            const int gr1 = gr0 + 16;
            if (gr1 < M && row0 + 16 < M) {
                float v = acc1[nt][r] + bias;
                unsigned short h = f2bf(v);
                ehi[(size_t)gr1 * DIM + col] = h;
                elo[(size_t)gr1 * DIM + col] = f2bf(v - bf2f(h));
            }
        }
    }
}

// ---------------------------------------------------------------------------
// Fused QKV (LDS-free): A = trunk planes. Q f32 (split-precision), K,V bf16
// interleaved KV[M][256]. grid (391,2).
// ---------------------------------------------------------------------------
__global__ __launch_bounds__(256) void qkv_k(
    const unsigned short* __restrict__ ehi, const unsigned short* __restrict__ elo,
    const unsigned short* __restrict__ wfrag,
    float* __restrict__ Qb, unsigned short* __restrict__ KVb, int M)
{
    constexpr int KS = 4, NTp = 4;
    constexpr int FRp = NTp * KS * 64;   // 1024
    constexpr int MATFR = 4 * FRp;       // 2 comp x 2 phase
    const int lane = threadIdx.x & 63;
    const int m16 = lane & 15, q4 = lane >> 4;
    const int phase = blockIdx.y;
    const int pairIdx = blockIdx.x * 4 + (threadIdx.x >> 6);
    const int nPairs = (M + 31) >> 5;
    if (pairIdx >= nPairs) return;

    const int row0 = pairIdx * 32;
    const int rA0 = imin(row0 + m16, M - 1);
    const int rA1 = imin(row0 + 16 + m16, M - 1);

    s8v a0h[KS], a0l[KS], a1h[KS], a1l[KS];
#pragma unroll
    for (int ks = 0; ks < KS; ks++) {
        a0h[ks] = *(const s8v*)(ehi + (size_t)rA0 * DIM + ks * 32 + q4 * 8);
        a0l[ks] = *(const s8v*)(elo + (size_t)rA0 * DIM + ks * 32 + q4 * 8);
        a1h[ks] = *(const s8v*)(ehi + (size_t)rA1 * DIM + ks * 32 + q4 * 8);
        a1l[ks] = *(const s8v*)(elo + (size_t)rA1 * DIM + ks * 32 + q4 * 8);
    }

    f4v aQ0[NTp], aQ1[NTp], aK0[NTp], aK1[NTp], aV0[NTp], aV1[NTp];
#pragma unroll
    for (int nt = 0; nt < NTp; nt++) {
        aQ0[nt] = (f4v){0,0,0,0}; aQ1[nt] = (f4v){0,0,0,0};
        aK0[nt] = (f4v){0,0,0,0}; aK1[nt] = (f4v){0,0,0,0};
        aV0[nt] = (f4v){0,0,0,0}; aV1[nt] = (f4v){0,0,0,0};
    }

#pragma unroll
    for (int ks = 0; ks < KS; ks++) {
#pragma unroll
        for (int nt = 0; nt < NTp; nt++) {
            const size_t fi = ((size_t)(nt * KS + ks) * 64 + lane) * 8;
            s8v qh = *(const s8v*)(wfrag + (size_t)(0 * MATFR + (0 * 2 + phase) * FRp) * 8 + fi);
            s8v ql = *(const s8v*)(wfrag + (size_t)(0 * MATFR + (1 * 2 + phase) * FRp) * 8 + fi);
            s8v kh = *(const s8v*)(wfrag + (size_t)(1 * MATFR + (0 * 2 + phase) * FRp) * 8 + fi);
            s8v kl = *(const s8v*)(wfrag + (size_t)(1 * MATFR + (1 * 2 + phase) * FRp) * 8 + fi);
            s8v vh = *(const s8v*)(wfrag + (size_t)(2 * MATFR + (0 * 2 + phase) * FRp) * 8 + fi);
            aQ0[nt] = __builtin_amdgcn_mfma_f32_16x16x32_bf16(a0h[ks], qh, aQ0[nt], 0, 0, 0);
            aQ0[nt] = __builtin_amdgcn_mfma_f32_16x16x32_bf16(a0h[ks], ql, aQ0[nt], 0, 0, 0);
            aQ0[nt] = __builtin_amdgcn_mfma_f32_16x16x32_bf16(a0l[ks], qh, aQ0[nt], 0, 0, 0);
            aQ1[nt] = __builtin_amdgcn_mfma_f32_16x16x32_bf16(a1h[ks], qh, aQ1[nt], 0, 0, 0);
            aQ1[nt] = __builtin_amdgcn_mfma_f32_16x16x32_bf16(a1h[ks], ql, aQ1[nt], 0, 0, 0);
            aQ1[nt] = __builtin_amdgcn_mfma_f32_16x16x32_bf16(a1l[ks], qh, aQ1[nt], 0, 0, 0);
            aK0[nt] = __builtin_amdgcn_mfma_f32_16x16x32_bf16(a0h[ks], kh, aK0[nt], 0, 0, 0);
            aK0[nt] = __builtin_amdgcn_mfma_f32_16x16x32_bf16(a0h[ks], kl, aK0[nt], 0, 0, 0);
            aK0[nt] = __builtin_amdgcn_mfma_f32_16x16x32_bf16(a0l[ks], kh, aK0[nt], 0, 0, 0);
            aK1[nt] = __builtin_amdgcn_mfma_f32_16x16x32_bf16(a1h[ks], kh, aK1[nt], 0, 0, 0);
            aK1[nt] = __builtin_amdgcn_mfma_f32_16x16x32_bf16(a1h[ks], kl, aK1[nt], 0, 0, 0);
            aK1[nt] = __builtin_amdgcn_mfma_f32_16x16x32_bf16(a1l[ks], kh, aK1[nt], 0, 0, 0);
            aV0[nt] = __builtin_amdgcn_mfma_f32_16x16x32_bf16(a0h[ks], vh, aV0[nt], 0, 0, 0);
            aV0[nt] = __builtin_amdgcn_mfma_f32_16x16x32_bf16(a0l[ks], vh, aV0[nt], 0, 0, 0);
            aV1[nt] = __builtin_amdgcn_mfma_f32_16x16x32_bf16(a1h[ks], vh, aV1[nt], 0, 0, 0);
            aV1[nt] = __builtin_amdgcn_mfma_f32_16x16x32_bf16(a1l[ks], vh, aV1[nt], 0, 0, 0);
        }
    }

#pragma unroll
    for (int nt = 0; nt < NTp; nt++) {
        const int col = phase * 64 + nt * 16 + m16;
#pragma unroll
        for (int r = 0; r < 4; r++) {
            const int gr0 = row0 + q4 * 4 + r;
            if (gr0 < M) {
                Qb[(size_t)gr0 * DIM + col] = aQ0[nt][r];
                KVb[(size_t)gr0 * 256 + col] = f2bf(aK0[nt][r]);
                KVb[(size_t)gr0 * 256 + 128 + col] = f2bf(aV0[nt][r]);
            }
            const int gr1 = gr0 + 16;
            if (gr1 < M && row0 + 16 < M) {
                Qb[(size_t)gr1 * DIM + col] = aQ1[nt][r];
                KVb[(size_t)gr1 * 256 + col] = f2bf(aK1[nt][r]);
                KVb[(size_t)gr1 * 256 + 128 + col] = f2bf(aV1[nt][r]);
            }
        }
    }
}

// ---------------------------------------------------------------------------
// Output projection (LDS-free): d_out(f32)[M,256] = trunk @ inv_w + inv_b.
// ---------------------------------------------------------------------------
__global__ __launch_bounds__(256) void outproj_k(
    const unsigned short* __restrict__ ehi, const unsigned short* __restrict__ elo,
    const unsigned short* __restrict__ wfrag, const float* __restrict__ b0,
    float* __restrict__ Out, int M)
{
    constexpr int KS = 4, NTp = 8, NOUT = 256;
    constexpr int FRp = NTp * KS * 64;  // 2048
    const int lane = threadIdx.x & 63;
    const int m16 = lane & 15, q4 = lane >> 4;
    const int phase = blockIdx.y;
    const int pairIdx = blockIdx.x * 4 + (threadIdx.x >> 6);
    const int nPairs = (M + 31) >> 5;
    if (pairIdx >= nPairs) return;

    const int row0 = pairIdx * 32;
    const int rA0 = imin(row0 + m16, M - 1);
    const int rA1 = imin(row0 + 16 + m16, M - 1);

    s8v a0h[KS], a0l[KS], a1h[KS], a1l[KS];
#pragma unroll
    for (int ks = 0; ks < KS; ks++) {
        a0h[ks] = *(const s8v*)(ehi + (size_t)rA0 * DIM + ks * 32 + q4 * 8);
        a0l[ks] = *(const s8v*)(elo + (size_t)rA0 * DIM + ks * 32 + q4 * 8);
        a1h[ks] = *(const s8v*)(ehi + (size_t)rA1 * DIM + ks * 32 + q4 * 8);
        a1l[ks] = *(const s8v*)(elo + (size_t)rA1 * DIM + ks * 32 + q4 * 8);
    }

    f4v acc0[NTp], acc1[NTp];
#pragma unroll
    for (int nt = 0; nt < NTp; nt++) { acc0[nt] = (f4v){0,0,0,0}; acc1[nt] = (f4v){0,0,0,0}; }

#pragma unroll
    for (int ks = 0; ks < KS; ks++) {
#pragma unroll
        for (int nt = 0; nt < NTp; nt++) {
            s8v b = *(const s8v*)(wfrag + ((size_t)phase * FRp + (size_t)(nt * KS + ks) * 64 + lane) * 8);
            acc0[nt] = __builtin_amdgcn_mfma_f32_16x16x32_bf16(a0h[ks], b, acc0[nt], 0, 0, 0);
            acc0[nt] = __builtin_amdgcn_mfma_f32_16x16x32_bf16(a0l[ks], b, acc0[nt], 0, 0, 0);
            acc1[nt] = __builtin_amdgcn_mfma_f32_16x16x32_bf16(a1h[ks], b, acc1[nt], 0, 0, 0);
            acc1[nt] = __builtin_amdgcn_mfma_f32_16x16x32_bf16(a1l[ks], b, acc1[nt], 0, 0, 0);
        }
    }

#pragma unroll
    for (int nt = 0; nt < NTp; nt++) {
        const int col = phase * 128 + nt * 16 + m16;
        const float bias = b0[col];
#pragma unroll
        for (int r = 0; r < 4; r++) {
            const int gr0 = row0 + q4 * 4 + r;
            if (gr0 < M) Out[(size_t)gr0 * NOUT + col] = acc0[nt][r] + bias;
            const int gr1 = gr0 + 16;
            if (gr1 < M && row0 + 16 < M) Out[(size_t)gr1 * NOUT + col] = acc1[nt][r] + bias;
        }
    }
}

// ---------------------------------------------------------------------------
// Fused attention + residual + LayerNorm. One wave per node; lane owns dims
// (2*lane, 2*lane+1); head = lane>>3. 4-edge chunks, double-buffered prefetch
// (8 loads in flight). Q f32; KV interleaved bf16; trunk hi/lo bf16 planes.
// ---------------------------------------------------------------------------
__global__ __launch_bounds__(256) void agg_k(
    const float* __restrict__ Q, const unsigned short* __restrict__ KV,
    const int* __restrict__ rowPtr, const int* __restrict__ colIdx,
    const float* __restrict__ ln_s, const float* __restrict__ ln_b,
    unsigned short* __restrict__ ehi, unsigned short* __restrict__ elo, int n)
{
    const int node = blockIdx.x * 4 + (threadIdx.x >> 6);
    if (node >= n) return;
    const int lane = threadIdx.x & 63;
    const int d = lane * 2;

    const float2 q = *(const float2*)(Q + (size_t)node * DIM + d);
    const unsigned int rh = *(const unsigned int*)(ehi + (size_t)node * DIM + d);
    const unsigned int rl = *(const unsigned int*)(elo + (size_t)node * DIM + d);
    const float r0 = bf2f(rh & 0xffffu) + bf2f(rl & 0xffffu);
    const float r1 = bf2f(rh >> 16) + bf2f(rl >> 16);

    const int e0 = rowPtr[node], e1 = rowPtr[node + 1];
    float acc0 = 0.f, acc1 = 0.f, den = 0.f;

    if (e1 > e0) {
        unsigned int kA[4], vA[4], kB[4], vB[4];
#define LOADC(karr, varr, base_)                                        \
        {                                                               \
            _Pragma("unroll")                                           \
            for (int j = 0; j < 4; j++) {                               \
                int idx = (base_) + j;                                  \
                int cc = colIdx[idx < e1 ? idx : e1 - 1];               \
                size_t off = (size_t)cc * 256 + d;                      \
                karr[j] = *(const unsigned int*)(KV + off);             \
                varr[j] = *(const unsigned int*)(KV + off + 128);       \
            }                                                           \
        }
#define COMP(karr, varr, base_)                                         \
        {                                                               \
            _Pragma("unroll")                                           \
            for (int j = 0; j < 4; j++) {                               \
                if ((base_) + j < e1) {                                 \
                    float p = q.x * bf2f(karr[j] & 0xffffu)             \
                            + q.y * bf2f(karr[j] >> 16);                \
                    p += __shfl_xor(p, 1);                              \
                    p += __shfl_xor(p, 2);                              \
                    p += __shfl_xor(p, 4);                              \
                    p = fminf(fmaxf(p, -10.f), 10.f);                   \
                    float w = __expf(p);                                \
                    den += w;                                           \
                    acc0 += w * bf2f(varr[j] & 0xffffu);                \
                    acc1 += w * bf2f(varr[j] >> 16);                    \
                }                                                       \
            }                                                           \
        }
        int base = e0;
        LOADC(kA, vA, base)
        while (base < e1) {
            int nxt = base + 4;
            if (nxt < e1) LOADC(kB, vB, nxt)
            COMP(kA, vA, base)
            base = nxt;
            if (base >= e1) break;
            int nxt2 = base + 4;
            if (nxt2 < e1) LOADC(kA, vA, nxt2)
            COMP(kB, vB, base)
            base = nxt2;
        }
#undef LOADC
#undef COMP
    }
    const float inv = 1.f / (den + 1e-8f);
    const float o0 = acc0 * inv + r0;
    const float o1 = acc1 * inv + r1;

    float s = o0 + o1, s2 = o0 * o0 + o1 * o1;
#pragma unroll
    for (int m = 1; m < 64; m <<= 1) {
        s  += __shfl_xor(s, m);
        s2 += __shfl_xor(s2, m);
    }
    const float mu = s * (1.f / 128.f);
    const float var = s2 * (1.f / 128.f) - mu * mu;
    const float rs = rsqrtf(var + 1e-6f);
    const float y0 = (o0 - mu) * rs * ln_s[d] + ln_b[d];
    const float y1 = (o1 - mu) * rs * ln_s[d + 1] + ln_b[d + 1];
    const unsigned short h0 = f2bf(y0), h1 = f2bf(y1);
    const unsigned short l0 = f2bf(y0 - bf2f(h0)), l1 = f2bf(y1 - bf2f(h1));
    *(unsigned int*)(ehi + (size_t)node * DIM + d) = (unsigned int)h0 | ((unsigned int)h1 << 16);
    *(unsigned int*)(elo + (size_t)node * DIM + d) = (unsigned int)l0 | ((unsigned int)l1 << 16);
}

// ---------------------------------------------------------------------------
// Launch
// ---------------------------------------------------------------------------
extern "C" void kernel_launch(void* const* d_in, const int* in_sizes, int n_in,
                              void* d_out, int out_size, void* d_ws, size_t ws_size,
                              hipStream_t stream)
{
    const float* x    = (const float*)d_in[0];
    const void*  ei   = d_in[1];
    const float* Wp   = (const float*)d_in[2];
    const float* Wpb  = (const float*)d_in[3];
    const float* Wpos = (const float*)d_in[4];
    const float* q1   = (const float*)d_in[5];
    const float* k1   = (const float*)d_in[6];
    const float* v1   = (const float*)d_in[7];
    const float* l1s  = (const float*)d_in[8];
    const float* l1b  = (const float*)d_in[9];
    const float* q2   = (const float*)d_in[10];
    const float* k2   = (const float*)d_in[11];
    const float* v2   = (const float*)d_in[12];
    const float* l2s  = (const float*)d_in[13];
    const float* l2b  = (const float*)d_in[14];
    const float* invw = (const float*)d_in[15];
    const float* invb = (const float*)d_in[16];

    const int N = in_sizes[0] / 256;   // 50000
    const int E = in_sizes[1] / 2;     // 800000

    char* p = (char*)d_ws;
    auto carve = [&](size_t bytes) -> void* {
        void* r = (void*)p;
        p += (bytes + 255) & ~(size_t)255;
        return r;
    };
    unsigned short* ehi = (unsigned short*)carve((size_t)N * DIM * 2);
    unsigned short* elo = (unsigned short*)carve((size_t)N * DIM * 2);
    float*          Qb  = (float*)carve((size_t)N * DIM * 4);
    unsigned short* KVb = (unsigned short*)carve((size_t)N * 256 * 2);
    int*   deg    = (int*)carve((size_t)N * 4);
    int*   incl   = (int*)carve((size_t)N * 4);
    int*   blkS   = (int*)carve(1024);
    int*   rowPtr = (int*)carve((size_t)(N + 1) * 4);
    int*   cursor = (int*)carve((size_t)N * 4);
    int*   colIdx = (int*)carve((size_t)E * 4);
    int*   rc     = (int*)carve((size_t)2 * E * 4);
    unsigned short* wfragP    = (unsigned short*)carve((size_t)2 * 256 * 128 * 2);
    unsigned short* wfragQKV1 = (unsigned short*)carve((size_t)3 * 2 * 128 * 128 * 2);
    unsigned short* wfragQKV2 = (unsigned short*)carve((size_t)3 * 2 * 128 * 128 * 2);
    unsigned short* wfragO    = (unsigned short*)carve((size_t)128 * 256 * 2);

    int* rows = rc;
    int* cols = rc + E;

    const int nb  = (N + 255) / 256;
    const int ebl = (E + 255) / 256;
    const int nPairs = (N + 31) / 32;
    const dim3 ggrid((nPairs + 3) / 4, 2);

    // CSR build (fused setup: dtype sniff + convert + degree count)
    hipMemsetAsync(deg, 0, (size_t)N * 4, stream);
    setup_k<<<(2 * E + 255) / 256, 256, 0, stream>>>(ei, 2 * E, E, rc, deg);
    scan1_k<<<nb, 256, 0, stream>>>(deg, N, incl, blkS);
    scan2_k<<<1, 256, 0, stream>>>(blkS, nb);
    scan3_k<<<nb, 256, 0, stream>>>(incl, deg, blkS, N, rowPtr, cursor);
    scatter_k<<<ebl, 256, 0, stream>>>(rows, cols, E, cursor, colIdx);

    // all weight fragments in one launch
    build_all_wfrag_k<<<144, 256, 0, stream>>>(Wp, q1, k1, v1, q2, k2, v2, invw,
                                               wfragP, wfragQKV1, wfragQKV2, wfragO);

    // input projection -> trunk planes
    proj_k<<<ggrid, 256, 0, stream>>>(x, wfragP, Wpb, Wpos, ehi, elo, N);

    // layer 1
    qkv_k<<<ggrid, 256, 0, stream>>>(ehi, elo, wfragQKV1, Qb, KVb, N);
    agg_k<<<(N + 3) / 4, 256, 0, stream>>>(Qb, KVb, rowPtr, colIdx, l1s, l1b, ehi, elo, N);

    // layer 2
    qkv_k<<<ggrid, 256, 0, stream>>>(ehi, elo, wfragQKV2, Qb, KVb, N);
    agg_k<<<(N + 3) / 4, 256, 0, stream>>>(Qb, KVb, rowPtr, colIdx, l2s, l2b, ehi, elo, N);

    // output projection
    outproj_k<<<ggrid, 256, 0, stream>>>(ehi, elo, wfragO, invb, (float*)d_out, N);
}